// Round 6
// baseline (365.571 us; speedup 1.0000x reference)
//
#include <hip/hip_runtime.h>

#define NN 4096
#define HEADS 4
#define H1PER 30
#define H1DIM 120
#define H2DIM 50

typedef short short8_t __attribute__((ext_vector_type(8)));
typedef float f32x4 __attribute__((ext_vector_type(4)));

__device__ __forceinline__ float lrelu(float x) { return x > 0.f ? x : 0.1f * x; }

// round-to-nearest-even float->bf16
__device__ __forceinline__ unsigned short bfrne(float x) {
  unsigned u = __float_as_uint(x);
  u += 0x7fffu + ((u >> 16) & 1u);
  return (unsigned short)(u >> 16);
}
__device__ __forceinline__ unsigned bfpk_rne(float lo, float hi) {
  return (unsigned)bfrne(lo) | ((unsigned)bfrne(hi) << 16);
}
// pack two floats to bf16x2 (round-half-up; for nonneg alpha weights)
__device__ __forceinline__ unsigned bfpk(float lo, float hi) {
  unsigned a = (__float_as_uint(lo) + 0x8000u) >> 16;
  unsigned b = (__float_as_uint(hi) + 0x8000u) & 0xffff0000u;
  return a | b;
}
// alpha-weight: exp(lrelu(f1+f2) - m) * maskbit
__device__ __forceinline__ float score(float f2v, float f1r, float mr, unsigned bsel, int jj) {
  float f = f1r + f2v;
  float e = fmaxf(f, 0.1f * f);
  float wv = __expf(e - mr);
  return wv * (float)((bsel >> jj) & 1u);
}

// ---------------- bitmask: adj(int32) -> 1 bit (4 elems/thread) ----------------
__global__ __launch_bounds__(256) void k_bits(const int* __restrict__ adj,
                                              unsigned long long* __restrict__ bits) {
  size_t base = (size_t)blockIdx.x * 1024;
  int t = threadIdx.x;
  int v0 = adj[base + t];
  int v1 = adj[base + 256 + t];
  int v2 = adj[base + 512 + t];
  int v3 = adj[base + 768 + t];
  unsigned long long m0 = __ballot(v0 > 0);
  unsigned long long m1 = __ballot(v1 > 0);
  unsigned long long m2 = __ballot(v2 > 0);
  unsigned long long m3 = __ballot(v3 > 0);
  if ((t & 63) == 0) {
    size_t w = (base + t) >> 6;
    bits[w] = m0;
    bits[w + 4] = m1;
    bits[w + 8] = m2;
    bits[w + 12] = m3;
  }
}

// ---------------- prep: W1 -> bf16 w1t[128][4096]; cols 120..127 = f1/f2 features ----------------
__global__ __launch_bounds__(256) void k_prep(const float* __restrict__ W1,
                                              const float* __restrict__ a1s,
                                              const float* __restrict__ a1d,
                                              unsigned short* __restrict__ w1t) {
  int k = blockIdx.x * 256 + threadIdx.x;  // 0..4095
#pragma unroll
  for (int h = 0; h < 4; ++h) {
    const float* wp = W1 + ((size_t)h * 4096 + k) * H1PER;
    float fs = 0.f, fd = 0.f;
#pragma unroll
    for (int oo = 0; oo < H1PER; ++oo) {
      float v = wp[oo];
      w1t[(size_t)(h * 30 + oo) * 4096 + k] = bfrne(v);
      fs += v * a1s[h * H1PER + oo];
      fd += v * a1d[h * H1PER + oo];
    }
    w1t[(size_t)(120 + h) * 4096 + k] = bfrne(fs);
    w1t[(size_t)(124 + h) * 4096 + k] = bfrne(fd);
  }
}

// ---------------- MFMA GEMM1 (LDS-free, double-buffered): part[z] = x[:, z*256:+256] @ w1t^T ----
// grid (64 mblocks, 16 ksplit), block 256 (4 waves; wave = 16-row m-tile x 128 cols)
// A-fragment loads straight from global (16 rows x 128B = full cache lines).
// Register double-buffer: iteration k+1's 10 loads issue before iteration k's 8 MFMAs.
__global__ __launch_bounds__(256) void k_gemm1s(const float* __restrict__ x,
                                                const unsigned short* __restrict__ w1t,
                                                float* __restrict__ part) {
  const int t = threadIdx.x;
  const int lane = t & 63, wave = t >> 6;
  const int m = lane & 15, q = lane >> 4;
  const int i0 = blockIdx.x * 64;
  const int kz = blockIdx.y * 256;
  const float* xp = x + (size_t)(i0 + wave * 16 + m) * 4096 + kz + q * 8;
  const unsigned short* wb = w1t + (size_t)m * 4096 + kz + q * 8;
  f32x4 acc[8];
#pragma unroll
  for (int nt = 0; nt < 8; ++nt) acc[nt] = (f32x4){0.f, 0.f, 0.f, 0.f};
  float4 a0[2], a1[2];
  short8_t Bv[2][8];
  a0[0] = *(const float4*)(xp);
  a1[0] = *(const float4*)(xp + 4);
#pragma unroll
  for (int nt = 0; nt < 8; ++nt) Bv[0][nt] = *(const short8_t*)(wb + (size_t)nt * 16 * 4096);
#pragma unroll
  for (int ks = 0; ks < 8; ++ks) {
    const int cur = ks & 1, nxt = cur ^ 1;
    if (ks < 7) {
      a0[nxt] = *(const float4*)(xp + (ks + 1) * 32);
      a1[nxt] = *(const float4*)(xp + (ks + 1) * 32 + 4);
#pragma unroll
      for (int nt = 0; nt < 8; ++nt)
        Bv[nxt][nt] = *(const short8_t*)(wb + (ks + 1) * 32 + (size_t)nt * 16 * 4096);
    }
    union { short8_t v; unsigned u[4]; } A;
    A.u[0] = bfpk_rne(a0[cur].x, a0[cur].y);
    A.u[1] = bfpk_rne(a0[cur].z, a0[cur].w);
    A.u[2] = bfpk_rne(a1[cur].x, a1[cur].y);
    A.u[3] = bfpk_rne(a1[cur].z, a1[cur].w);
#pragma unroll
    for (int nt = 0; nt < 8; ++nt)
      acc[nt] = __builtin_amdgcn_mfma_f32_16x16x32_bf16(A.v, Bv[cur][nt], acc[nt], 0, 0, 0);
  }
  // C/D: row = q*4+reg, col = m (per 16-col n-tile)
  float* pp = part + ((size_t)blockIdx.y * 4096 + i0 + wave * 16 + q * 4) * 128 + m;
#pragma unroll
  for (int nt = 0; nt < 8; ++nt)
#pragma unroll
    for (int r = 0; r < 4; ++r) pp[r * 128 + nt * 16] = acc[nt][r];
}

// ---------------- combine 16 k-split partials -> whbt(bf16,T) + f1/f2 ----------------
// grid 256 blocks, 256 threads: 16 nodes/block, 16 threads/node (8 cols each)
__global__ __launch_bounds__(256) void k_f1c(const float* __restrict__ part,
                                             unsigned short* __restrict__ whbt,
                                             float* __restrict__ f1, float* __restrict__ f2) {
  const int t = threadIdx.x;
  const int n = blockIdx.x * 16 + (t >> 4);
  const int og = (t & 15) * 8;
  float s[8] = {0.f, 0.f, 0.f, 0.f, 0.f, 0.f, 0.f, 0.f};
  for (int z = 0; z < 16; ++z) {
    const float* pp = part + ((size_t)z * NN + n) * 128 + og;
    float4 u0 = *(const float4*)pp;
    float4 u1 = *(const float4*)(pp + 4);
    s[0] += u0.x; s[1] += u0.y; s[2] += u0.z; s[3] += u0.w;
    s[4] += u1.x; s[5] += u1.y; s[6] += u1.z; s[7] += u1.w;
  }
  if (og < 120) {
#pragma unroll
    for (int j = 0; j < 8; ++j) {
      int o = og + j;
      int h = o / 30, oo = o - h * 30;
      whbt[(size_t)(h * 32 + oo) * NN + n] = bfrne(s[j]);
    }
  } else {
#pragma unroll
    for (int j = 0; j < 4; ++j) {
      f1[(size_t)j * NN + n] = s[j];
      f2[(size_t)j * NN + n] = s[4 + j];
    }
  }
  if ((t & 15) < 8) {
    int h = (t & 15) >> 1, odd = (t & 15) & 1;
    whbt[(size_t)(h * 32 + 30 + odd) * NN + n] = odd ? 0 : 0x3f80;
  }
}

// ---------------- per-row max over 4096 values ----------------
__global__ __launch_bounds__(256) void k_max(const float* __restrict__ v, float* __restrict__ mx) {
  int t = threadIdx.x;
  const float* row = v + (size_t)blockIdx.x * NN;
  float m = -3.0e38f;
  for (int n = t; n < NN; n += 256) m = fmaxf(m, row[n]);
  for (int off = 32; off > 0; off >>= 1) m = fmaxf(m, __shfl_down(m, off));
  __shared__ float ms[4];
  if ((t & 63) == 0) ms[t >> 6] = m;
  __syncthreads();
  if (t == 0) mx[blockIdx.x] = fmaxf(fmaxf(ms[0], ms[1]), fmaxf(ms[2], ms[3]));
}

// ---------------- MFMA attention layer 1 ----------------
// grid (64 i-blocks, 4 heads, 2 j-split), block 256 (4 waves x 16 rows)
__global__ __launch_bounds__(256) void k_att1m(const unsigned short* __restrict__ whbt,
                                               const float* __restrict__ f1, const float* __restrict__ f2,
                                               const float* __restrict__ mx,
                                               const unsigned int* __restrict__ bits32,
                                               float* __restrict__ part) {
  const int h = blockIdx.y, js = blockIdx.z;
  const int t = threadIdx.x;
  const int lane = t & 63, wave = t >> 6;
  const int m = lane & 15, q = lane >> 4;
  const int i0 = blockIdx.x * 64 + wave * 16;
  const int jbase = js * 2048;
  __shared__ float f2s[2048];
  for (int e = t; e < 2048; e += 256) f2s[e] = f2[h * NN + jbase + e];
  __syncthreads();
  const float f1r = f1[h * NN + i0 + m];
  const float fm = f1r + mx[h];
  const float mr = fmaxf(fm, 0.1f * fm);
  const unsigned int* brow = bits32 + (size_t)(i0 + m) * 128 + (jbase >> 5);
  const unsigned short* bb0 = whbt + (size_t)(h * 32 + m) * NN + jbase + q * 8;
  const unsigned short* bb1 = bb0 + 16 * NN;
  const float* fp = f2s + q * 8;
  f32x4 acc0 = {0.f, 0.f, 0.f, 0.f}, acc1 = {0.f, 0.f, 0.f, 0.f};
  for (int step = 0; step < 64; ++step) {
    const int jl = step * 32;
    unsigned bsel = brow[step] >> (q * 8);
    float4 fa = *(const float4*)(fp + jl);
    float4 fb = *(const float4*)(fp + jl + 4);
    float w0 = score(fa.x, f1r, mr, bsel, 0);
    float w1 = score(fa.y, f1r, mr, bsel, 1);
    float w2 = score(fa.z, f1r, mr, bsel, 2);
    float w3 = score(fa.w, f1r, mr, bsel, 3);
    float w4 = score(fb.x, f1r, mr, bsel, 4);
    float w5 = score(fb.y, f1r, mr, bsel, 5);
    float w6 = score(fb.z, f1r, mr, bsel, 6);
    float w7 = score(fb.w, f1r, mr, bsel, 7);
    union { short8_t v; unsigned u[4]; } A;
    A.u[0] = bfpk(w0, w1);
    A.u[1] = bfpk(w2, w3);
    A.u[2] = bfpk(w4, w5);
    A.u[3] = bfpk(w6, w7);
    short8_t b0 = *(const short8_t*)(bb0 + jl);
    short8_t b1 = *(const short8_t*)(bb1 + jl);
    acc0 = __builtin_amdgcn_mfma_f32_16x16x32_bf16(A.v, b0, acc0, 0, 0, 0);
    acc1 = __builtin_amdgcn_mfma_f32_16x16x32_bf16(A.v, b1, acc1, 0, 0, 0);
  }
  float* pp = part + ((size_t)(js * 4 + h) * NN + i0 + q * 4) * 32 + m;
#pragma unroll
  for (int r = 0; r < 4; ++r) {
    pp[r * 32] = acc0[r];
    pp[r * 32 + 16] = acc1[r];
  }
}

// ---------------- combine layer-1 partials -> h1 ----------------
// grid 2048, block 256: 8 (h,n) ids per block (16384 total)
__global__ __launch_bounds__(256) void k_h1(const float* __restrict__ part, const float* __restrict__ b1,
                                            float* __restrict__ h1) {
  int t = threadIdx.x;
  int lane = t & 63;
  int p = lane >> 5, o = lane & 31;
  int id = blockIdx.x * 8 + (t >> 6) * 2 + p;  // h*4096+n
  int h = id >> 12, n = id & 4095;
  const float* p0 = part + ((size_t)h * NN + n) * 32 + o;
  const float* p1 = part + ((size_t)(4 + h) * NN + n) * 32 + o;
  float tot = p0[0] + p1[0];
  float l = __shfl(tot, p * 32 + 30);
  if (o < H1PER) h1[(size_t)n * H1DIM + h * H1PER + o] = lrelu(tot / l + b1[h * H1PER + o]);
}

// ---------------- GEMM2: wh2 = h1 @ W2 ----------------
__global__ __launch_bounds__(256) void k_gemm2(const float* __restrict__ h1, const float* __restrict__ W2,
                                               float* __restrict__ wh2) {
  const int n0 = blockIdx.x * 4;
  const int t = threadIdx.x;
  const int o = t & 63, r = t >> 6;
  __shared__ float hs[4][120];
  for (int e = t; e < 4 * H1DIM; e += 256) hs[e / H1DIM][e % H1DIM] = h1[(size_t)n0 * H1DIM + e];
  __syncthreads();
  if (o < H2DIM) {
    float acc = 0.f;
#pragma unroll 4
    for (int k = 0; k < H1DIM; ++k) acc += hs[r][k] * W2[k * H2DIM + o];
    wh2[(size_t)(n0 + r) * H2DIM + o] = acc;
  }
}

// ---------------- layer-2 f1/f2 + bf16 wh2^T ----------------
__global__ __launch_bounds__(256) void k_f2l2(const float* __restrict__ wh2, const float* __restrict__ a2s,
                                              const float* __restrict__ a2d, float* __restrict__ f1,
                                              float* __restrict__ f2, unsigned short* __restrict__ whbt) {
  int n = blockIdx.x * 256 + threadIdx.x;
  if (n >= NN) return;
  const float* r = wh2 + (size_t)n * H2DIM;
  unsigned short* wb = whbt + n;
  float accs = 0.f, accd = 0.f;
#pragma unroll
  for (int j = 0; j < H2DIM; ++j) {
    float v = r[j];
    wb[j * NN] = bfrne(v);
    accs += v * a2s[j];
    accd += v * a2d[j];
  }
  wb[50 * NN] = 0x3f80;
#pragma unroll
  for (int j = 51; j < 64; ++j) wb[j * NN] = 0;
  f1[n] = accs;
  f2[n] = accd;
}

// ---------------- MFMA attention layer 2 ----------------
__global__ __launch_bounds__(256) void k_att2m(const unsigned short* __restrict__ whbt,
                                               const float* __restrict__ f1, const float* __restrict__ f2,
                                               const float* __restrict__ mx,
                                               const unsigned int* __restrict__ bits32,
                                               float* __restrict__ part) {
  const int js = blockIdx.y;
  const int t = threadIdx.x;
  const int lane = t & 63, wave = t >> 6;
  const int m = lane & 15, q = lane >> 4;
  const int i0 = blockIdx.x * 64 + wave * 16;
  const int jbase = js * 1024;
  __shared__ float f2s[1024];
  for (int e = t; e < 1024; e += 256) f2s[e] = f2[jbase + e];
  __syncthreads();
  const float f1r = f1[i0 + m];
  const float fm = f1r + mx[0];
  const float mr = fmaxf(fm, 0.1f * fm);
  const unsigned int* brow = bits32 + (size_t)(i0 + m) * 128 + (jbase >> 5);
  const unsigned short* bb = whbt + (size_t)m * NN + jbase + q * 8;
  const float* fp = f2s + q * 8;
  f32x4 acc[4];
#pragma unroll
  for (int x = 0; x < 4; ++x) acc[x] = (f32x4){0.f, 0.f, 0.f, 0.f};
  for (int step = 0; step < 32; ++step) {
    const int jl = step * 32;
    unsigned bsel = brow[step] >> (q * 8);
    float4 fa = *(const float4*)(fp + jl);
    float4 fb = *(const float4*)(fp + jl + 4);
    float w0 = score(fa.x, f1r, mr, bsel, 0);
    float w1 = score(fa.y, f1r, mr, bsel, 1);
    float w2 = score(fa.z, f1r, mr, bsel, 2);
    float w3 = score(fa.w, f1r, mr, bsel, 3);
    float w4 = score(fb.x, f1r, mr, bsel, 4);
    float w5 = score(fb.y, f1r, mr, bsel, 5);
    float w6 = score(fb.z, f1r, mr, bsel, 6);
    float w7 = score(fb.w, f1r, mr, bsel, 7);
    union { short8_t v; unsigned u[4]; } A;
    A.u[0] = bfpk(w0, w1);
    A.u[1] = bfpk(w2, w3);
    A.u[2] = bfpk(w4, w5);
    A.u[3] = bfpk(w6, w7);
#pragma unroll
    for (int tile = 0; tile < 4; ++tile) {
      short8_t b = *(const short8_t*)(bb + (size_t)tile * 16 * NN + jl);
      acc[tile] = __builtin_amdgcn_mfma_f32_16x16x32_bf16(A.v, b, acc[tile], 0, 0, 0);
    }
  }
  float* pp = part + ((size_t)js * NN + i0 + q * 4) * 64 + m;
#pragma unroll
  for (int tile = 0; tile < 4; ++tile)
#pragma unroll
    for (int r = 0; r < 4; ++r) pp[r * 64 + tile * 16] = acc[tile][r];
}

// ---------------- combine layer-2 partials -> h2 ----------------
__global__ __launch_bounds__(64) void k_h2(const float* __restrict__ part, const float* __restrict__ b2,
                                           float* __restrict__ h2) {
  int n = blockIdx.x;
  int o = threadIdx.x;
  const float* p = part + (size_t)n * 64 + o;
  float tot = p[0] + p[NN * 64] + p[2 * NN * 64] + p[3 * NN * 64];
  float l = __shfl(tot, 50);
  if (o < H2DIM) h2[(size_t)n * H2DIM + o] = lrelu(tot / l + b2[o]);
}

// ---------------- FiLM + logits (wave-local, shuffle-based; 4 nodes/block) ----------------
__global__ __launch_bounds__(256) void k_film(const float* __restrict__ l_loc, const float* __restrict__ h2,
                                              const float* __restrict__ Wl1, const float* __restrict__ bl1,
                                              const float* __restrict__ Wl2, const float* __restrict__ bl2,
                                              const float* __restrict__ Wg, const float* __restrict__ bg,
                                              const float* __restrict__ Wb, const float* __restrict__ bb,
                                              const float* __restrict__ Wgate, const float* __restrict__ bgate,
                                              const float* __restrict__ Wc, float* __restrict__ logits) {
  int n = blockIdx.x * 4 + (threadIdx.x >> 6);
  int lane = threadIdx.x & 63;
  int r32 = lane & 31;
  float locv = l_loc[n * 16 + (lane & 15)];
  float cov = __shfl(locv, 15);
  cov = fminf(fmaxf(cov, 0.f), 1.f);
  float a1v = bl1[r32];
#pragma unroll
  for (int j = 0; j < 16; ++j) a1v += Wl1[r32 * 16 + j] * __shfl(locv, j);
  float z1 = lrelu(a1v);
  float a2v = bl2[r32];
#pragma unroll
  for (int j = 0; j < 32; ++j) a2v += Wl2[r32 * 32 + j] * __shfl(z1, j);
  float z2 = lrelu(a2v);
  float gs = bgate[0];
  float gam, bet;
  {
    int o = lane < H2DIM ? lane : 0;
    gam = bg[o];
    bet = bb[o];
#pragma unroll
    for (int j = 0; j < 32; ++j) {
      float zj = __shfl(z2, j);
      gs += Wgate[j] * zj;
      gam += Wg[o * 32 + j] * zj;
      bet += Wb[o * 32 + j] * zj;
    }
  }
  float g = cov / (1.f + __expf(-gs));
  int o = lane < H2DIM ? lane : 0;
  float hv = h2[(size_t)n * H2DIM + o];
  float hf = hv + g * (gam * hv + bet);
  float p0 = lane < H2DIM ? hf * Wc[o] : 0.f;
  float p1 = lane < H2DIM ? hf * Wc[H2DIM + o] : 0.f;
  for (int off = 32; off > 0; off >>= 1) {
    p0 += __shfl_down(p0, off);
    p1 += __shfl_down(p1, off);
  }
  if (lane == 0) {
    logits[n * 2 + 0] = lrelu(p0);
    logits[n * 2 + 1] = lrelu(p1);
  }
}

// ---------------- SSDB ----------------
__global__ __launch_bounds__(64) void k_ssdb1(const float* __restrict__ logits, const float* __restrict__ Ws1,
                                              float* __restrict__ hsum) {
  int combo = blockIdx.y;
  int hemi = combo >> 1, c = combo & 1;
  int k = threadIdx.x;
  if (k >= 60) return;
  int nbase = blockIdx.x * 256;
  const float* wrow = Ws1 + (size_t)k * 2048 + nbase;
  const float* lcol = logits + (size_t)(hemi * 2048 + nbase) * 2 + c;
  float part = 0.f;
  for (int q = 0; q < 256; ++q) part += wrow[q] * lcol[2 * q];
  atomicAdd(&hsum[combo * 60 + k], part);
}

__global__ __launch_bounds__(256) void k_ssdb2(const float* __restrict__ hsum, const float* __restrict__ bs1,
                                               const float* __restrict__ Ws2, const float* __restrict__ bs2,
                                               float* __restrict__ B) {
  int t = threadIdx.x;
  int combo = t >> 6, k = t & 63;
  float part = 0.f;
  if (k < 60) part = lrelu(hsum[combo * 60 + k] + bs1[k]) * Ws2[k];
  for (int off = 32; off > 0; off >>= 1) part += __shfl_down(part, off);
  if (k == 0) B[combo] = lrelu(part + bs2[0]);
}

__global__ __launch_bounds__(256) void k_final(const float* __restrict__ logits, const float* __restrict__ B,
                                               float* __restrict__ out) {
  int id = blockIdx.x * 256 + threadIdx.x;
  if (id < 2 * NN) {
    int n = id >> 1, c = id & 1;
    out[id] = logits[id] + B[(n < 2048 ? 0 : 2) + c];
  } else if (id < 2 * NN + 2) {
    int c = id - 2 * NN;
    out[id] = 0.5f * (B[c] + B[2 + c]);
  }
}

// ---------------- workspace layout (float offsets) ----------------
// persistent-early: BITS, W1T. GP [16][4096][128] dead after k_f1c; everything
// downstream overlays GP's region. WH1BT/F1A/F2A/MX1 live during k_f1c -> placed after GP.
#define OFF_BITS 0          // 524288 (u64 bitmask)
#define OFF_W1T 524288      // 262144 (bf16 [128][4096])
#define OFF_GP 786432       // 8388608 (gemm1 partials [16][4096][128])
#define OFF_A1P 786432      // 1048576 (att1 partials; overlays dead GP)
#define OFF_A2P 1835008     // 1048576 (att2 partials; overlays dead GP)
#define OFF_H1 2883584      // 491520
#define OFF_WH2 3375104     // 204800
#define OFF_WH2BT 3579904   // 131072
#define OFF_F12 3710976     // 4096
#define OFF_F22 3715072     // 4096
#define OFF_MX2 3719168     // 64
#define OFF_H2 3719232      // 204800
#define OFF_LOG 3924032     // 8192
#define OFF_HSUM 3932224    // 256
#define OFF_B 3932480       // 8
#define OFF_WH1BT 9175040   // 262144 (bf16 [4][32][4096]; coexists with GP)
#define OFF_F1A 9437184     // 16384
#define OFF_F2A 9453568     // 16384
#define OFF_MX1 9469952     // 64   -> total 9470016 floats = 37.9 MB

extern "C" void kernel_launch(void* const* d_in, const int* in_sizes, int n_in,
                              void* d_out, int out_size, void* d_ws, size_t ws_size,
                              hipStream_t stream) {
  const float* x_fc  = (const float*)d_in[0];
  const int*   adj   = (const int*)d_in[1];
  const float* l_loc = (const float*)d_in[2];
  const float* W1    = (const float*)d_in[3];
  const float* a1s   = (const float*)d_in[4];
  const float* a1d   = (const float*)d_in[5];
  const float* b1    = (const float*)d_in[6];
  const float* W2    = (const float*)d_in[7];
  const float* a2s   = (const float*)d_in[8];
  const float* a2d   = (const float*)d_in[9];
  const float* b2    = (const float*)d_in[10];
  const float* Wc    = (const float*)d_in[11];
  const float* Wl1   = (const float*)d_in[12];
  const float* bl1   = (const float*)d_in[13];
  const float* Wl2   = (const float*)d_in[14];
  const float* bl2   = (const float*)d_in[15];
  const float* Wg    = (const float*)d_in[16];
  const float* bg    = (const float*)d_in[17];
  const float* Wb    = (const float*)d_in[18];
  const float* bb    = (const float*)d_in[19];
  const float* Wgate = (const float*)d_in[20];
  const float* bgate = (const float*)d_in[21];
  const float* Ws1   = (const float*)d_in[22];
  const float* bs1   = (const float*)d_in[23];
  const float* Ws2   = (const float*)d_in[24];
  const float* bs2   = (const float*)d_in[25];
  float* out = (float*)d_out;
  float* w = (float*)d_ws;
  unsigned long long* bits = (unsigned long long*)(w + OFF_BITS);
  const unsigned int* bits32 = (const unsigned int*)bits;
  unsigned short* wh1bt = (unsigned short*)(w + OFF_WH1BT);
  unsigned short* wh2bt = (unsigned short*)(w + OFF_WH2BT);
  unsigned short* w1t = (unsigned short*)(w + OFF_W1T);

  k_bits<<<NN * NN / 1024, 256, 0, stream>>>(adj, bits);
  k_prep<<<16, 256, 0, stream>>>(W1, a1s, a1d, w1t);
  k_gemm1s<<<dim3(64, 16), 256, 0, stream>>>(x_fc, w1t, w + OFF_GP);
  k_f1c<<<256, 256, 0, stream>>>(w + OFF_GP, wh1bt, w + OFF_F1A, w + OFF_F2A);
  k_max<<<HEADS, 256, 0, stream>>>(w + OFF_F2A, w + OFF_MX1);
  k_att1m<<<dim3(64, HEADS, 2), 256, 0, stream>>>(wh1bt, w + OFF_F1A, w + OFF_F2A,
                                                  w + OFF_MX1, bits32, w + OFF_A1P);
  k_h1<<<2048, 256, 0, stream>>>(w + OFF_A1P, b1, w + OFF_H1);
  k_gemm2<<<NN / 4, 256, 0, stream>>>(w + OFF_H1, W2, w + OFF_WH2);
  k_f2l2<<<NN / 256, 256, 0, stream>>>(w + OFF_WH2, a2s, a2d, w + OFF_F12, w + OFF_F22, wh2bt);
  k_max<<<1, 256, 0, stream>>>(w + OFF_F22, w + OFF_MX2);
  k_att2m<<<dim3(64, 4), 256, 0, stream>>>(wh2bt, w + OFF_F12, w + OFF_F22,
                                           w + OFF_MX2, bits32, w + OFF_A2P);
  k_h2<<<NN, 64, 0, stream>>>(w + OFF_A2P, b2, w + OFF_H2);
  k_film<<<NN / 4, 256, 0, stream>>>(l_loc, w + OFF_H2, Wl1, bl1, Wl2, bl2, Wg, bg, Wb, bb,
                                     Wgate, bgate, Wc, w + OFF_LOG);
  hipMemsetAsync(w + OFF_HSUM, 0, 240 * sizeof(float), stream);
  k_ssdb1<<<dim3(8, 4), 64, 0, stream>>>(w + OFF_LOG, Ws1, w + OFF_HSUM);
  k_ssdb2<<<1, 256, 0, stream>>>(w + OFF_HSUM, bs1, Ws2, bs2, w + OFF_B);
  k_final<<<(2 * NN + 2 + 255) / 256, 256, 0, stream>>>(w + OFF_LOG, w + OFF_B, out);
}

// Round 7
// 359.245 us; speedup vs baseline: 1.0176x; 1.0176x over previous
//
#include <hip/hip_runtime.h>

#define NN 4096
#define HEADS 4
#define H1PER 30
#define H1DIM 120
#define H2DIM 50

typedef short short8_t __attribute__((ext_vector_type(8)));
typedef float f32x4 __attribute__((ext_vector_type(4)));

__device__ __forceinline__ float lrelu(float x) { return x > 0.f ? x : 0.1f * x; }

// round-to-nearest-even float->bf16
__device__ __forceinline__ unsigned short bfrne(float x) {
  unsigned u = __float_as_uint(x);
  u += 0x7fffu + ((u >> 16) & 1u);
  return (unsigned short)(u >> 16);
}
__device__ __forceinline__ unsigned bfpk_rne(float lo, float hi) {
  return (unsigned)bfrne(lo) | ((unsigned)bfrne(hi) << 16);
}
// pack two floats to bf16x2 (round-half-up; for nonneg alpha weights)
__device__ __forceinline__ unsigned bfpk(float lo, float hi) {
  unsigned a = (__float_as_uint(lo) + 0x8000u) >> 16;
  unsigned b = (__float_as_uint(hi) + 0x8000u) & 0xffff0000u;
  return a | b;
}
// alpha-weight: exp(lrelu(f1+f2) - m) * maskbit
__device__ __forceinline__ float score(float f2v, float f1r, float mr, unsigned bsel, int jj) {
  float f = f1r + f2v;
  float e = fmaxf(f, 0.1f * f);
  float wv = __expf(e - mr);
  return wv * (float)((bsel >> jj) & 1u);
}

// async global->LDS, 16B per lane; dest = wave-uniform base + lane*16
#define GL16(g, l)                                                                        \
  __builtin_amdgcn_global_load_lds((const __attribute__((address_space(1))) unsigned int*)(g), \
                                   (__attribute__((address_space(3))) unsigned int*)(l), 16, 0, 0)

// ---------------- bitmask: adj(int32) -> 1 bit (4 elems/thread) ----------------
__global__ __launch_bounds__(256) void k_bits(const int* __restrict__ adj,
                                              unsigned long long* __restrict__ bits) {
  size_t base = (size_t)blockIdx.x * 1024;
  int t = threadIdx.x;
  int v0 = adj[base + t];
  int v1 = adj[base + 256 + t];
  int v2 = adj[base + 512 + t];
  int v3 = adj[base + 768 + t];
  unsigned long long m0 = __ballot(v0 > 0);
  unsigned long long m1 = __ballot(v1 > 0);
  unsigned long long m2 = __ballot(v2 > 0);
  unsigned long long m3 = __ballot(v3 > 0);
  if ((t & 63) == 0) {
    size_t w = (base + t) >> 6;
    bits[w] = m0;
    bits[w + 4] = m1;
    bits[w + 8] = m2;
    bits[w + 12] = m3;
  }
}

// ---------------- prep: W1 -> bf16 w1t[128][4096]; cols 120..127 = f1/f2 features ----------------
__global__ __launch_bounds__(256) void k_prep(const float* __restrict__ W1,
                                              const float* __restrict__ a1s,
                                              const float* __restrict__ a1d,
                                              unsigned short* __restrict__ w1t) {
  int k = blockIdx.x * 256 + threadIdx.x;  // 0..4095
#pragma unroll
  for (int h = 0; h < 4; ++h) {
    const float* wp = W1 + ((size_t)h * 4096 + k) * H1PER;
    float fs = 0.f, fd = 0.f;
#pragma unroll
    for (int oo = 0; oo < H1PER; ++oo) {
      float v = wp[oo];
      w1t[(size_t)(h * 30 + oo) * 4096 + k] = bfrne(v);
      fs += v * a1s[h * H1PER + oo];
      fd += v * a1d[h * H1PER + oo];
    }
    w1t[(size_t)(120 + h) * 4096 + k] = bfrne(fs);
    w1t[(size_t)(124 + h) * 4096 + k] = bfrne(fd);
  }
}

// ---------------- MFMA GEMM1 v3 (global_load_lds staging): part[z] = x[:, z*512:+512] @ w1t^T ---
// grid (128 mblocks(32 rows), 8 ksplit), block 256 (4 waves).
// wave w: rows (w&1)*16..+15, col-tiles nt=(w>>1)*4..+3.
// x staged to LDS via async DMA (16B/lane, chunk-XOR swizzle to kill bank conflicts);
// B frags straight from L2-resident w1t.
__global__ __launch_bounds__(256) void k_gemm1s(const float* __restrict__ x,
                                                const unsigned short* __restrict__ w1t,
                                                float* __restrict__ part) {
  const int t = threadIdx.x;
  const int lane = t & 63, wave = t >> 6;
  const int m = lane & 15, q = lane >> 4;
  const int i0 = blockIdx.x * 32;
  const int kz = blockIdx.y * 512;
  __shared__ float xs[32 * 64];  // [row][chunk-slot]: slot c holds global chunk c^(row&7)
  const int r0 = (wave & 1) * 16;
  const int ntg0 = (wave >> 1) * 4;
  // staging rows for this thread's two DMA instructions
  const int srow0 = wave * 8 + q;
  const int srow1 = srow0 + 4;
  const int sc0 = m ^ (srow0 & 7);
  const int sc1 = m ^ (srow1 & 7);
  const float* gx0 = x + (size_t)(i0 + srow0) * 4096 + kz + sc0 * 4;
  const float* gx1 = x + (size_t)(i0 + srow1) * 4096 + kz + sc1 * 4;
  float* ls0 = &xs[srow0 * 64 + m * 4];
  float* ls1 = &xs[srow1 * 64 + m * 4];
  const int arow = r0 + m;
  const int asw = (m & 7);
  f32x4 acc[4];
#pragma unroll
  for (int nt = 0; nt < 4; ++nt) acc[nt] = (f32x4){0.f, 0.f, 0.f, 0.f};
  for (int it = 0; it < 8; ++it) {
    const int kc = it * 64;
    GL16(gx0 + kc, ls0);
    GL16(gx1 + kc, ls1);
    __syncthreads();
#pragma unroll
    for (int ks2 = 0; ks2 < 2; ++ks2) {
      const int c0 = ks2 * 8 + q * 2;
      float4 a0 = *(const float4*)&xs[arow * 64 + ((c0 ^ asw) * 4)];
      float4 a1 = *(const float4*)&xs[arow * 64 + (((c0 + 1) ^ asw) * 4)];
      union { short8_t v; unsigned u[4]; } A;
      A.u[0] = bfpk_rne(a0.x, a0.y);
      A.u[1] = bfpk_rne(a0.z, a0.w);
      A.u[2] = bfpk_rne(a1.x, a1.y);
      A.u[3] = bfpk_rne(a1.z, a1.w);
      const unsigned short* wp = w1t + (size_t)m * 4096 + kz + kc + ks2 * 32 + q * 8;
#pragma unroll
      for (int nt = 0; nt < 4; ++nt) {
        short8_t B = *(const short8_t*)(wp + (size_t)(ntg0 + nt) * 16 * 4096);
        acc[nt] = __builtin_amdgcn_mfma_f32_16x16x32_bf16(A.v, B, acc[nt], 0, 0, 0);
      }
    }
    __syncthreads();
  }
  // C/D: row = q*4+reg, col = m (per 16-col n-tile)
  float* pp = part + ((size_t)blockIdx.y * 4096 + i0 + r0 + q * 4) * 128 + ntg0 * 16 + m;
#pragma unroll
  for (int nt = 0; nt < 4; ++nt)
#pragma unroll
    for (int r = 0; r < 4; ++r) pp[r * 128 + nt * 16] = acc[nt][r];
}

// ---------------- combine 8 k-split partials -> whbt(bf16,T) + f1/f2 ----------------
// grid 256 blocks, 256 threads: 16 nodes/block, 16 threads/node (8 cols each)
__global__ __launch_bounds__(256) void k_f1c(const float* __restrict__ part,
                                             unsigned short* __restrict__ whbt,
                                             float* __restrict__ f1, float* __restrict__ f2) {
  const int t = threadIdx.x;
  const int n = blockIdx.x * 16 + (t >> 4);
  const int og = (t & 15) * 8;
  float s[8] = {0.f, 0.f, 0.f, 0.f, 0.f, 0.f, 0.f, 0.f};
  for (int z = 0; z < 8; ++z) {
    const float* pp = part + ((size_t)z * NN + n) * 128 + og;
    float4 u0 = *(const float4*)pp;
    float4 u1 = *(const float4*)(pp + 4);
    s[0] += u0.x; s[1] += u0.y; s[2] += u0.z; s[3] += u0.w;
    s[4] += u1.x; s[5] += u1.y; s[6] += u1.z; s[7] += u1.w;
  }
  if (og < 120) {
#pragma unroll
    for (int j = 0; j < 8; ++j) {
      int o = og + j;
      int h = o / 30, oo = o - h * 30;
      whbt[(size_t)(h * 32 + oo) * NN + n] = bfrne(s[j]);
    }
  } else {
#pragma unroll
    for (int j = 0; j < 4; ++j) {
      f1[(size_t)j * NN + n] = s[j];
      f2[(size_t)j * NN + n] = s[4 + j];
    }
  }
  if ((t & 15) < 8) {
    int h = (t & 15) >> 1, odd = (t & 15) & 1;
    whbt[(size_t)(h * 32 + 30 + odd) * NN + n] = odd ? 0 : 0x3f80;
  }
}

// ---------------- per-row max over 4096 values ----------------
__global__ __launch_bounds__(256) void k_max(const float* __restrict__ v, float* __restrict__ mx) {
  int t = threadIdx.x;
  const float* row = v + (size_t)blockIdx.x * NN;
  float m = -3.0e38f;
  for (int n = t; n < NN; n += 256) m = fmaxf(m, row[n]);
  for (int off = 32; off > 0; off >>= 1) m = fmaxf(m, __shfl_down(m, off));
  __shared__ float ms[4];
  if ((t & 63) == 0) ms[t >> 6] = m;
  __syncthreads();
  if (t == 0) mx[blockIdx.x] = fmaxf(fmaxf(ms[0], ms[1]), fmaxf(ms[2], ms[3]));
}

// ---------------- MFMA attention layer 1 ----------------
// grid (64 i-blocks, 4 heads, 2 j-split), block 256 (4 waves x 16 rows)
__global__ __launch_bounds__(256) void k_att1m(const unsigned short* __restrict__ whbt,
                                               const float* __restrict__ f1, const float* __restrict__ f2,
                                               const float* __restrict__ mx,
                                               const unsigned int* __restrict__ bits32,
                                               float* __restrict__ part) {
  const int h = blockIdx.y, js = blockIdx.z;
  const int t = threadIdx.x;
  const int lane = t & 63, wave = t >> 6;
  const int m = lane & 15, q = lane >> 4;
  const int i0 = blockIdx.x * 64 + wave * 16;
  const int jbase = js * 2048;
  __shared__ float f2s[2048];
  for (int e = t; e < 2048; e += 256) f2s[e] = f2[h * NN + jbase + e];
  __syncthreads();
  const float f1r = f1[h * NN + i0 + m];
  const float fm = f1r + mx[h];
  const float mr = fmaxf(fm, 0.1f * fm);
  const unsigned int* brow = bits32 + (size_t)(i0 + m) * 128 + (jbase >> 5);
  const unsigned short* bb0 = whbt + (size_t)(h * 32 + m) * NN + jbase + q * 8;
  const unsigned short* bb1 = bb0 + 16 * NN;
  const float* fp = f2s + q * 8;
  f32x4 acc0 = {0.f, 0.f, 0.f, 0.f}, acc1 = {0.f, 0.f, 0.f, 0.f};
  for (int step = 0; step < 64; ++step) {
    const int jl = step * 32;
    unsigned bsel = brow[step] >> (q * 8);
    float4 fa = *(const float4*)(fp + jl);
    float4 fb = *(const float4*)(fp + jl + 4);
    float w0 = score(fa.x, f1r, mr, bsel, 0);
    float w1 = score(fa.y, f1r, mr, bsel, 1);
    float w2 = score(fa.z, f1r, mr, bsel, 2);
    float w3 = score(fa.w, f1r, mr, bsel, 3);
    float w4 = score(fb.x, f1r, mr, bsel, 4);
    float w5 = score(fb.y, f1r, mr, bsel, 5);
    float w6 = score(fb.z, f1r, mr, bsel, 6);
    float w7 = score(fb.w, f1r, mr, bsel, 7);
    union { short8_t v; unsigned u[4]; } A;
    A.u[0] = bfpk(w0, w1);
    A.u[1] = bfpk(w2, w3);
    A.u[2] = bfpk(w4, w5);
    A.u[3] = bfpk(w6, w7);
    short8_t b0 = *(const short8_t*)(bb0 + jl);
    short8_t b1 = *(const short8_t*)(bb1 + jl);
    acc0 = __builtin_amdgcn_mfma_f32_16x16x32_bf16(A.v, b0, acc0, 0, 0, 0);
    acc1 = __builtin_amdgcn_mfma_f32_16x16x32_bf16(A.v, b1, acc1, 0, 0, 0);
  }
  float* pp = part + ((size_t)(js * 4 + h) * NN + i0 + q * 4) * 32 + m;
#pragma unroll
  for (int r = 0; r < 4; ++r) {
    pp[r * 32] = acc0[r];
    pp[r * 32 + 16] = acc1[r];
  }
}

// ---------------- combine layer-1 partials -> h1 ----------------
// grid 2048, block 256: 8 (h,n) ids per block (16384 total)
__global__ __launch_bounds__(256) void k_h1(const float* __restrict__ part, const float* __restrict__ b1,
                                            float* __restrict__ h1) {
  int t = threadIdx.x;
  int lane = t & 63;
  int p = lane >> 5, o = lane & 31;
  int id = blockIdx.x * 8 + (t >> 6) * 2 + p;  // h*4096+n
  int h = id >> 12, n = id & 4095;
  const float* p0 = part + ((size_t)h * NN + n) * 32 + o;
  const float* p1 = part + ((size_t)(4 + h) * NN + n) * 32 + o;
  float tot = p0[0] + p1[0];
  float l = __shfl(tot, p * 32 + 30);
  if (o < H1PER) h1[(size_t)n * H1DIM + h * H1PER + o] = lrelu(tot / l + b1[h * H1PER + o]);
}

// ---------------- GEMM2: wh2 = h1 @ W2 ----------------
__global__ __launch_bounds__(256) void k_gemm2(const float* __restrict__ h1, const float* __restrict__ W2,
                                               float* __restrict__ wh2) {
  const int n0 = blockIdx.x * 4;
  const int t = threadIdx.x;
  const int o = t & 63, r = t >> 6;
  __shared__ float hs[4][120];
  for (int e = t; e < 4 * H1DIM; e += 256) hs[e / H1DIM][e % H1DIM] = h1[(size_t)n0 * H1DIM + e];
  __syncthreads();
  if (o < H2DIM) {
    float acc = 0.f;
#pragma unroll 4
    for (int k = 0; k < H1DIM; ++k) acc += hs[r][k] * W2[k * H2DIM + o];
    wh2[(size_t)(n0 + r) * H2DIM + o] = acc;
  }
}

// ---------------- layer-2 f1/f2 + bf16 wh2^T ----------------
__global__ __launch_bounds__(256) void k_f2l2(const float* __restrict__ wh2, const float* __restrict__ a2s,
                                              const float* __restrict__ a2d, float* __restrict__ f1,
                                              float* __restrict__ f2, unsigned short* __restrict__ whbt) {
  int n = blockIdx.x * 256 + threadIdx.x;
  if (n >= NN) return;
  const float* r = wh2 + (size_t)n * H2DIM;
  unsigned short* wb = whbt + n;
  float accs = 0.f, accd = 0.f;
#pragma unroll
  for (int j = 0; j < H2DIM; ++j) {
    float v = r[j];
    wb[j * NN] = bfrne(v);
    accs += v * a2s[j];
    accd += v * a2d[j];
  }
  wb[50 * NN] = 0x3f80;
#pragma unroll
  for (int j = 51; j < 64; ++j) wb[j * NN] = 0;
  f1[n] = accs;
  f2[n] = accd;
}

// ---------------- MFMA attention layer 2 ----------------
__global__ __launch_bounds__(256) void k_att2m(const unsigned short* __restrict__ whbt,
                                               const float* __restrict__ f1, const float* __restrict__ f2,
                                               const float* __restrict__ mx,
                                               const unsigned int* __restrict__ bits32,
                                               float* __restrict__ part) {
  const int js = blockIdx.y;
  const int t = threadIdx.x;
  const int lane = t & 63, wave = t >> 6;
  const int m = lane & 15, q = lane >> 4;
  const int i0 = blockIdx.x * 64 + wave * 16;
  const int jbase = js * 1024;
  __shared__ float f2s[1024];
  for (int e = t; e < 1024; e += 256) f2s[e] = f2[jbase + e];
  __syncthreads();
  const float f1r = f1[i0 + m];
  const float fm = f1r + mx[0];
  const float mr = fmaxf(fm, 0.1f * fm);
  const unsigned int* brow = bits32 + (size_t)(i0 + m) * 128 + (jbase >> 5);
  const unsigned short* bb = whbt + (size_t)m * NN + jbase + q * 8;
  const float* fp = f2s + q * 8;
  f32x4 acc[4];
#pragma unroll
  for (int x = 0; x < 4; ++x) acc[x] = (f32x4){0.f, 0.f, 0.f, 0.f};
  for (int step = 0; step < 32; ++step) {
    const int jl = step * 32;
    unsigned bsel = brow[step] >> (q * 8);
    float4 fa = *(const float4*)(fp + jl);
    float4 fb = *(const float4*)(fp + jl + 4);
    float w0 = score(fa.x, f1r, mr, bsel, 0);
    float w1 = score(fa.y, f1r, mr, bsel, 1);
    float w2 = score(fa.z, f1r, mr, bsel, 2);
    float w3 = score(fa.w, f1r, mr, bsel, 3);
    float w4 = score(fb.x, f1r, mr, bsel, 4);
    float w5 = score(fb.y, f1r, mr, bsel, 5);
    float w6 = score(fb.z, f1r, mr, bsel, 6);
    float w7 = score(fb.w, f1r, mr, bsel, 7);
    union { short8_t v; unsigned u[4]; } A;
    A.u[0] = bfpk(w0, w1);
    A.u[1] = bfpk(w2, w3);
    A.u[2] = bfpk(w4, w5);
    A.u[3] = bfpk(w6, w7);
#pragma unroll
    for (int tile = 0; tile < 4; ++tile) {
      short8_t b = *(const short8_t*)(bb + (size_t)tile * 16 * NN + jl);
      acc[tile] = __builtin_amdgcn_mfma_f32_16x16x32_bf16(A.v, b, acc[tile], 0, 0, 0);
    }
  }
  float* pp = part + ((size_t)js * NN + i0 + q * 4) * 64 + m;
#pragma unroll
  for (int tile = 0; tile < 4; ++tile)
#pragma unroll
    for (int r = 0; r < 4; ++r) pp[r * 64 + tile * 16] = acc[tile][r];
}

// ---------------- combine layer-2 partials -> h2 ----------------
__global__ __launch_bounds__(64) void k_h2(const float* __restrict__ part, const float* __restrict__ b2,
                                           float* __restrict__ h2) {
  int n = blockIdx.x;
  int o = threadIdx.x;
  const float* p = part + (size_t)n * 64 + o;
  float tot = p[0] + p[NN * 64] + p[2 * NN * 64] + p[3 * NN * 64];
  float l = __shfl(tot, 50);
  if (o < H2DIM) h2[(size_t)n * H2DIM + o] = lrelu(tot / l + b2[o]);
}

// ---------------- FiLM + logits (wave-local, shuffle-based; 4 nodes/block) ----------------
__global__ __launch_bounds__(256) void k_film(const float* __restrict__ l_loc, const float* __restrict__ h2,
                                              const float* __restrict__ Wl1, const float* __restrict__ bl1,
                                              const float* __restrict__ Wl2, const float* __restrict__ bl2,
                                              const float* __restrict__ Wg, const float* __restrict__ bg,
                                              const float* __restrict__ Wb, const float* __restrict__ bb,
                                              const float* __restrict__ Wgate, const float* __restrict__ bgate,
                                              const float* __restrict__ Wc, float* __restrict__ logits) {
  int n = blockIdx.x * 4 + (threadIdx.x >> 6);
  int lane = threadIdx.x & 63;
  int r32 = lane & 31;
  float locv = l_loc[n * 16 + (lane & 15)];
  float cov = __shfl(locv, 15);
  cov = fminf(fmaxf(cov, 0.f), 1.f);
  float a1v = bl1[r32];
#pragma unroll
  for (int j = 0; j < 16; ++j) a1v += Wl1[r32 * 16 + j] * __shfl(locv, j);
  float z1 = lrelu(a1v);
  float a2v = bl2[r32];
#pragma unroll
  for (int j = 0; j < 32; ++j) a2v += Wl2[r32 * 32 + j] * __shfl(z1, j);
  float z2 = lrelu(a2v);
  float gs = bgate[0];
  float gam, bet;
  {
    int o = lane < H2DIM ? lane : 0;
    gam = bg[o];
    bet = bb[o];
#pragma unroll
    for (int j = 0; j < 32; ++j) {
      float zj = __shfl(z2, j);
      gs += Wgate[j] * zj;
      gam += Wg[o * 32 + j] * zj;
      bet += Wb[o * 32 + j] * zj;
    }
  }
  float g = cov / (1.f + __expf(-gs));
  int o = lane < H2DIM ? lane : 0;
  float hv = h2[(size_t)n * H2DIM + o];
  float hf = hv + g * (gam * hv + bet);
  float p0 = lane < H2DIM ? hf * Wc[o] : 0.f;
  float p1 = lane < H2DIM ? hf * Wc[H2DIM + o] : 0.f;
  for (int off = 32; off > 0; off >>= 1) {
    p0 += __shfl_down(p0, off);
    p1 += __shfl_down(p1, off);
  }
  if (lane == 0) {
    logits[n * 2 + 0] = lrelu(p0);
    logits[n * 2 + 1] = lrelu(p1);
  }
}

// ---------------- SSDB ----------------
__global__ __launch_bounds__(64) void k_ssdb1(const float* __restrict__ logits, const float* __restrict__ Ws1,
                                              float* __restrict__ hsum) {
  int combo = blockIdx.y;
  int hemi = combo >> 1, c = combo & 1;
  int k = threadIdx.x;
  if (k >= 60) return;
  int nbase = blockIdx.x * 256;
  const float* wrow = Ws1 + (size_t)k * 2048 + nbase;
  const float* lcol = logits + (size_t)(hemi * 2048 + nbase) * 2 + c;
  float part = 0.f;
  for (int q = 0; q < 256; ++q) part += wrow[q] * lcol[2 * q];
  atomicAdd(&hsum[combo * 60 + k], part);
}

__global__ __launch_bounds__(256) void k_ssdb2(const float* __restrict__ hsum, const float* __restrict__ bs1,
                                               const float* __restrict__ Ws2, const float* __restrict__ bs2,
                                               float* __restrict__ B) {
  int t = threadIdx.x;
  int combo = t >> 6, k = t & 63;
  float part = 0.f;
  if (k < 60) part = lrelu(hsum[combo * 60 + k] + bs1[k]) * Ws2[k];
  for (int off = 32; off > 0; off >>= 1) part += __shfl_down(part, off);
  if (k == 0) B[combo] = lrelu(part + bs2[0]);
}

__global__ __launch_bounds__(256) void k_final(const float* __restrict__ logits, const float* __restrict__ B,
                                               float* __restrict__ out) {
  int id = blockIdx.x * 256 + threadIdx.x;
  if (id < 2 * NN) {
    int n = id >> 1, c = id & 1;
    out[id] = logits[id] + B[(n < 2048 ? 0 : 2) + c];
  } else if (id < 2 * NN + 2) {
    int c = id - 2 * NN;
    out[id] = 0.5f * (B[c] + B[2 + c]);
  }
}

// ---------------- workspace layout (float offsets) ----------------
// (round-6 layout kept; GP region oversized for ksplit 8 — harmless)
#define OFF_BITS 0          // 524288 (u64 bitmask)
#define OFF_W1T 524288      // 262144 (bf16 [128][4096])
#define OFF_GP 786432       // gemm1 partials [8][4096][128] (4194304 used)
#define OFF_A1P 786432      // 1048576 (att1 partials; overlays dead GP)
#define OFF_A2P 1835008     // 1048576 (att2 partials; overlays dead GP)
#define OFF_H1 2883584      // 491520
#define OFF_WH2 3375104     // 204800
#define OFF_WH2BT 3579904   // 131072
#define OFF_F12 3710976     // 4096
#define OFF_F22 3715072     // 4096
#define OFF_MX2 3719168     // 64
#define OFF_H2 3719232      // 204800
#define OFF_LOG 3924032     // 8192
#define OFF_HSUM 3932224    // 256
#define OFF_B 3932480       // 8
#define OFF_WH1BT 9175040   // 262144 (bf16 [4][32][4096]; coexists with GP)
#define OFF_F1A 9437184     // 16384
#define OFF_F2A 9453568     // 16384
#define OFF_MX1 9469952     // 64

extern "C" void kernel_launch(void* const* d_in, const int* in_sizes, int n_in,
                              void* d_out, int out_size, void* d_ws, size_t ws_size,
                              hipStream_t stream) {
  const float* x_fc  = (const float*)d_in[0];
  const int*   adj   = (const int*)d_in[1];
  const float* l_loc = (const float*)d_in[2];
  const float* W1    = (const float*)d_in[3];
  const float* a1s   = (const float*)d_in[4];
  const float* a1d   = (const float*)d_in[5];
  const float* b1    = (const float*)d_in[6];
  const float* W2    = (const float*)d_in[7];
  const float* a2s   = (const float*)d_in[8];
  const float* a2d   = (const float*)d_in[9];
  const float* b2    = (const float*)d_in[10];
  const float* Wc    = (const float*)d_in[11];
  const float* Wl1   = (const float*)d_in[12];
  const float* bl1   = (const float*)d_in[13];
  const float* Wl2   = (const float*)d_in[14];
  const float* bl2   = (const float*)d_in[15];
  const float* Wg    = (const float*)d_in[16];
  const float* bg    = (const float*)d_in[17];
  const float* Wb    = (const float*)d_in[18];
  const float* bb    = (const float*)d_in[19];
  const float* Wgate = (const float*)d_in[20];
  const float* bgate = (const float*)d_in[21];
  const float* Ws1   = (const float*)d_in[22];
  const float* bs1   = (const float*)d_in[23];
  const float* Ws2   = (const float*)d_in[24];
  const float* bs2   = (const float*)d_in[25];
  float* out = (float*)d_out;
  float* w = (float*)d_ws;
  unsigned long long* bits = (unsigned long long*)(w + OFF_BITS);
  const unsigned int* bits32 = (const unsigned int*)bits;
  unsigned short* wh1bt = (unsigned short*)(w + OFF_WH1BT);
  unsigned short* wh2bt = (unsigned short*)(w + OFF_WH2BT);
  unsigned short* w1t = (unsigned short*)(w + OFF_W1T);

  k_bits<<<NN * NN / 1024, 256, 0, stream>>>(adj, bits);
  k_prep<<<16, 256, 0, stream>>>(W1, a1s, a1d, w1t);
  k_gemm1s<<<dim3(128, 8), 256, 0, stream>>>(x_fc, w1t, w + OFF_GP);
  k_f1c<<<256, 256, 0, stream>>>(w + OFF_GP, wh1bt, w + OFF_F1A, w + OFF_F2A);
  k_max<<<HEADS, 256, 0, stream>>>(w + OFF_F2A, w + OFF_MX1);
  k_att1m<<<dim3(64, HEADS, 2), 256, 0, stream>>>(wh1bt, w + OFF_F1A, w + OFF_F2A,
                                                  w + OFF_MX1, bits32, w + OFF_A1P);
  k_h1<<<2048, 256, 0, stream>>>(w + OFF_A1P, b1, w + OFF_H1);
  k_gemm2<<<NN / 4, 256, 0, stream>>>(w + OFF_H1, W2, w + OFF_WH2);
  k_f2l2<<<NN / 256, 256, 0, stream>>>(w + OFF_WH2, a2s, a2d, w + OFF_F12, w + OFF_F22, wh2bt);
  k_max<<<1, 256, 0, stream>>>(w + OFF_F22, w + OFF_MX2);
  k_att2m<<<dim3(64, 4), 256, 0, stream>>>(wh2bt, w + OFF_F12, w + OFF_F22,
                                           w + OFF_MX2, bits32, w + OFF_A2P);
  k_h2<<<NN, 64, 0, stream>>>(w + OFF_A2P, b2, w + OFF_H2);
  k_film<<<NN / 4, 256, 0, stream>>>(l_loc, w + OFF_H2, Wl1, bl1, Wl2, bl2, Wg, bg, Wb, bb,
                                     Wgate, bgate, Wc, w + OFF_LOG);
  hipMemsetAsync(w + OFF_HSUM, 0, 240 * sizeof(float), stream);
  k_ssdb1<<<dim3(8, 4), 64, 0, stream>>>(w + OFF_LOG, Ws1, w + OFF_HSUM);
  k_ssdb2<<<1, 256, 0, stream>>>(w + OFF_HSUM, bs1, Ws2, bs2, w + OFF_B);
  k_final<<<(2 * NN + 2 + 255) / 256, 256, 0, stream>>>(w + OFF_LOG, w + OFF_B, out);
}